// Round 8
// baseline (59.926 us; speedup 1.0000x reference)
//
#include <hip/hip_runtime.h>

#define M_AG   4608
#define NPO    1536
#define D_DIM  256
#define H_DIM  512
#define NBIG   1536
#define GRID_SZ 256
#define NB_CAP 48

typedef __attribute__((ext_vector_type(8))) short short8;
typedef __attribute__((ext_vector_type(4))) float f32x4;
typedef unsigned short ushort_t;
typedef unsigned long long u64;

struct Args {
  const float *S, *W_out, *W_in, *W1, *W2, *b_out, *b_in, *b1, *b2;
  const float *energies, *resource_grid;
  const int *roles, *positions;
  ushort_t *Sc, *Wc, *W2c, *Abf, *Bbf;
  int4 *stats;
  int *nbl;
  float *out;
};

__device__ __forceinline__ ushort_t f2bf(float f) {
  unsigned int u = __builtin_bit_cast(unsigned int, f);
  unsigned int r = (u + 0x7FFFu + ((u >> 16) & 1u)) >> 16;   // RNE, finite inputs
  return (ushort_t)r;
}
__device__ __forceinline__ float bf2f(ushort_t u) {
  return __builtin_bit_cast(float, (unsigned int)u << 16);
}
__device__ __forceinline__ float tanh_fast(float x) {
  float e = __builtin_amdgcn_exp2f(x * 2.8853900817779268f);  // exp(2x)
  return 1.f - 2.f * __builtin_amdgcn_rcpf(e + 1.f);
}
__device__ __forceinline__ void gl_lds16(const ushort_t* g, ushort_t* l) {
  __builtin_amdgcn_global_load_lds(
      (const __attribute__((address_space(1))) unsigned int*)g,
      (__attribute__((address_space(3))) unsigned int*)l, 16, 0, 0);
}
#define VM0_BAR() do { asm volatile("s_waitcnt vmcnt(0)" ::: "memory"); \
                       __builtin_amdgcn_s_barrier(); } while (0)

// ---------------------------------------------------------------------------
// pack tasks (0..1343): Sc [32][4608][8], Wc [3][32][1536][8], W2c [3][64][256][8]
// ---------------------------------------------------------------------------
__device__ __forceinline__ void pack_task(const Args& A, int task) {
  const int t = threadIdx.x;
  if (task < 576) {
    int idx = task * 256 + t;
    int kc = idx / M_AG, m = idx - kc * M_AG;
    const float* p = A.S + (size_t)m * D_DIM + kc * 8;
    ushort_t* d = A.Sc + (size_t)idx * 8;
#pragma unroll
    for (int j = 0; j < 8; ++j) d[j] = f2bf(p[j]);
  } else if (task < 1152) {
    int idx = (task - 576) * 256 + t;
    int org = idx / (32 * NBIG);
    int rem = idx - org * (32 * NBIG);
    int kc = rem / NBIG, n = rem - kc * NBIG;
    int which = n >> 9, nl = n & 511;
    const float* Wsel = (which == 0 ? A.W_out : which == 1 ? A.W_in : A.W1);
    const float* p = Wsel + (size_t)org * (D_DIM * H_DIM) + (size_t)kc * 8 * H_DIM + nl;
    ushort_t* d = A.Wc + (size_t)idx * 8;
#pragma unroll
    for (int j = 0; j < 8; ++j) d[j] = f2bf(p[(size_t)j * H_DIM]);
  } else {
    int idx = (task - 1152) * 256 + t;
    int org = idx / (64 * D_DIM);
    int rem = idx - org * (64 * D_DIM);
    int kc = rem >> 8, n = rem & 255;
    const float* p = A.W2 + (size_t)org * (H_DIM * D_DIM) + (size_t)kc * 8 * D_DIM + n;
    ushort_t* d = A.W2c + (size_t)idx * 8;
#pragma unroll
    for (int j = 0; j < 8; ++j) d[j] = f2bf(p[(size_t)j * D_DIM]);
  }
}

// ---------------------------------------------------------------------------
// neighbor scan: 8 agents/task (wave/agent x2), ballot-ordered ascending list
// ---------------------------------------------------------------------------
__device__ __forceinline__ void scan_task(const Args& A, int stask, char* smem) {
  const int t = threadIdx.x;
  int* pk = (int*)smem;                 // x | y<<8 | role<<16
  u64* r0m = (u64*)(smem + 18432);
  u64* r1m = r0m + 72;
  for (int j = t; j < M_AG; j += 256) {
    int2 p2 = ((const int2*)A.positions)[j];
    pk[j] = p2.x | (p2.y << 8) | (A.roles[j] << 16);
  }
  __syncthreads();
  const int w = t >> 6, l = t & 63;
  for (int g = w; g < 72; g += 4) {
    int rj = pk[g * 64 + l] >> 16;
    u64 m0 = __ballot(rj == 0);
    u64 m1 = __ballot(rj == 1);
    if (l == 0) { r0m[g] = m0; r1m[g] = m1; }
  }
  __syncthreads();
  const int base_i = stask * 8;
#pragma unroll
  for (int rep = 0; rep < 2; ++rep) {
    const int i = base_i + rep * 4 + w;
    const int pi = pk[i];
    const int xi = pi & 255, yi = (pi >> 8) & 255;
    const int org = (i >= NPO) + (i >= 2 * NPO);   // org_ids = repeat(arange(3),1536)
    const int olo = org * NPO, ohi = olo + NPO;
    int nbn = 0, mass = 0, fi = 0, enemy = 0;
    for (int bs = olo; bs < ohi; bs += 64) {
      int j = bs + l;
      int pj = pk[j];
      int dx = (pj & 255) - xi, dy = ((pj >> 8) & 255) - yi;
      bool in_r = (dx * dx + dy * dy <= 25) && (j != i);
      u64 ms = __ballot(in_r);
      if (ms) {
        int g = bs >> 6;
        mass += __popcll(ms & r0m[g]);
        fi   += __popcll(ms & r1m[g]);
        if (in_r) {
          int slot = nbn + __popcll(ms & ((1ull << l) - 1ull));
          if (slot < NB_CAP) A.nbl[i * NB_CAP + slot] = j;
        }
        nbn += __popcll(ms);
      }
    }
#pragma unroll
    for (int half = 0; half < 2; ++half) {
      const int lo = half ? ohi : 0;
      const int hi = half ? M_AG : olo;
      for (int bs = lo; bs < hi; bs += 64) {
        int pj = pk[bs + l];
        int dx = (pj & 255) - xi, dy = ((pj >> 8) & 255) - yi;
        u64 ms = __ballot(dx * dx + dy * dy <= 25);
        enemy += __popcll(ms & r1m[bs >> 6]);
      }
    }
    if (l == 0) A.stats[i] = make_int4(nbn, mass, fi, enemy);
  }
}

// ---------------------------------------------------------------------------
// A/B GEMM tile (which 0/1): [A|B] = tanh(S*[W_out|W_in]+bias); 64x64, BK=64,
// dbuf LDS, STAGE(next) in flight across VM0_BAR (r7-proven).
// ---------------------------------------------------------------------------
__device__ __forceinline__ void gemm_tile(const Args& A, int tix, char* smem) {
  ushort_t* As = (ushort_t*)smem;
  ushort_t* Bs = (ushort_t*)(smem + 16384);
  const int t = threadIdx.x;
  const int w = t >> 6, l = t & 63;
  const int wm = w >> 1, wn = w & 1;
  const int lr = l & 15, lg = l >> 4;
  const int bx = tix & 15, by = tix >> 4;
  const int n0 = bx * 64, m0 = by * 64;
  const int org = m0 / NPO;
  const int which = n0 >> 9, nlb = n0 & 511;
  const int g0 = t >> 6, r0 = t & 63, g1 = 4 + g0;
  const size_t wbase = (size_t)org * 32;

  f32x4 acc[2][2] = {};

  auto STAGE = [&](int s, int p) {
    const int kg = s * 8;
    ushort_t* Ad = As + p * 4096;
    ushort_t* Bd = Bs + p * 4096;
    gl_lds16(A.Sc + ((size_t)(kg + g0) * M_AG + m0 + r0) * 8, Ad + (size_t)t * 8);
    gl_lds16(A.Sc + ((size_t)(kg + g1) * M_AG + m0 + r0) * 8, Ad + (size_t)(t + 256) * 8);
    gl_lds16(A.Wc + ((wbase + kg + g0) * NBIG + n0 + r0) * 8, Bd + (size_t)t * 8);
    gl_lds16(A.Wc + ((wbase + kg + g1) * NBIG + n0 + r0) * 8, Bd + (size_t)(t + 256) * 8);
  };

  STAGE(0, 0);
  VM0_BAR();
  for (int s = 0; s < 4; ++s) {
    const int p = s & 1;
    if (s < 3) STAGE(s + 1, p ^ 1);
    const short8* Ap = (const short8*)(As + p * 4096);
    const short8* Bp = (const short8*)(Bs + p * 4096);
    short8 af[2][2], bf_[2][2];
#pragma unroll
    for (int k2 = 0; k2 < 2; ++k2) {
#pragma unroll
      for (int mi = 0; mi < 2; ++mi)
        af[mi][k2] = Ap[(k2 * 4 + lg) * 64 + wm * 32 + mi * 16 + lr];
#pragma unroll
      for (int ni = 0; ni < 2; ++ni)
        bf_[ni][k2] = Bp[(k2 * 4 + lg) * 64 + wn * 32 + ni * 16 + lr];
    }
#pragma unroll
    for (int mi = 0; mi < 2; ++mi)
#pragma unroll
      for (int ni = 0; ni < 2; ++ni)
#pragma unroll
        for (int k2 = 0; k2 < 2; ++k2)
          acc[mi][ni] = __builtin_amdgcn_mfma_f32_16x16x32_bf16(
              af[mi][k2], bf_[ni][k2], acc[mi][ni], 0, 0, 0);
    VM0_BAR();
  }

  const float* bias = (which == 0 ? A.b_out : A.b_in) + (size_t)org * H_DIM;
  ushort_t* dst = (which == 0) ? A.Abf : A.Bbf;
#pragma unroll
  for (int ni = 0; ni < 2; ++ni) {
    const int nl = nlb + wn * 32 + ni * 16 + lr;
    const float bb = bias[nl];
#pragma unroll
    for (int mi = 0; mi < 2; ++mi)
#pragma unroll
      for (int r = 0; r < 4; ++r) {
        const int row = m0 + wm * 32 + mi * 16 + lg * 4 + r;
        dst[(size_t)row * H_DIM + nl] = f2bf(tanh_fast(acc[mi][ni][r] + bb));
      }
  }
}

// ---------------------------------------------------------------------------
// row_mlp: 32 rows/block. S-tile resident in LDS; for each 128-col chunk:
// GEMM1 H1c = tanh(S*W1c + b1c) (B=W1 direct-to-reg, no barriers) -> LDS;
// GEMM2 SPacc += H1c * W2c (B direct-to-reg). Epilogue writes out[:,0:256].
// ---------------------------------------------------------------------------
__device__ __forceinline__ void row_mlp(const Args& A, int blk, char* smem) {
  ushort_t* Sres = (ushort_t*)smem;             // [32 kg][32 row][8] = 16KB
  ushort_t* H1c  = (ushort_t*)(smem + 16384);   // [16 kg][32 row][8] = 8KB
  const int t = threadIdx.x;
  const int w = t >> 6, l = t & 63;
  const int lr = l & 15, lg = l >> 4;
  const int wn = w;                             // wave grid 1x4
  const int m0 = blk * 32;
  const int org = m0 / NPO;

#pragma unroll
  for (int j = 0; j < 4; ++j) {                 // S tile: 1024 chunks
    int c = j * 256 + t;
    int kg = c >> 5, row = c & 31;
    gl_lds16(A.Sc + ((size_t)kg * M_AG + m0 + row) * 8, Sres + (size_t)c * 8);
  }
  VM0_BAR();

  f32x4 sp[2][4] = {};                          // rows mi*16+lg*4+r, cols wn*64+ni*16+lr
  const short8* Sp = (const short8*)Sres;
  const short8* Hp = (const short8*)H1c;

#pragma unroll
  for (int c = 0; c < 4; ++c) {
    const int cbase = c * 128;
    f32x4 a1[2][2] = {};                        // H1 chunk: cols wn*32+ni*16+lr
#pragma unroll
    for (int s = 0; s < 4; ++s) {               // GEMM1: K=256, steps of 64
      short8 bq[2][2];
#pragma unroll
      for (int ni = 0; ni < 2; ++ni)
#pragma unroll
        for (int k2 = 0; k2 < 2; ++k2)
          bq[ni][k2] = *(const short8*)(A.Wc +
              ((size_t)(org * 32 + s * 8 + k2 * 4 + lg) * NBIG +
               1024 + cbase + wn * 32 + ni * 16 + lr) * 8);
      short8 af[2][2];
#pragma unroll
      for (int mi = 0; mi < 2; ++mi)
#pragma unroll
        for (int k2 = 0; k2 < 2; ++k2)
          af[mi][k2] = Sp[(s * 8 + k2 * 4 + lg) * 32 + mi * 16 + lr];
#pragma unroll
      for (int mi = 0; mi < 2; ++mi)
#pragma unroll
        for (int ni = 0; ni < 2; ++ni)
#pragma unroll
          for (int k2 = 0; k2 < 2; ++k2)
            a1[mi][ni] = __builtin_amdgcn_mfma_f32_16x16x32_bf16(
                af[mi][k2], bq[ni][k2], a1[mi][ni], 0, 0, 0);
    }
    __syncthreads();                            // H1c readers (prev c) done
#pragma unroll
    for (int mi = 0; mi < 2; ++mi)
#pragma unroll
      for (int ni = 0; ni < 2; ++ni) {
        const int col = wn * 32 + ni * 16 + lr;
        const float bb = A.b1[org * H_DIM + cbase + col];
#pragma unroll
        for (int r = 0; r < 4; ++r) {
          const int row = mi * 16 + lg * 4 + r;
          H1c[((size_t)(col >> 3) * 32 + row) * 8 + (col & 7)] =
              f2bf(tanh_fast(a1[mi][ni][r] + bb));
        }
      }
    __syncthreads();                            // H1c complete
#pragma unroll
    for (int s2 = 0; s2 < 2; ++s2) {            // GEMM2: K=128, steps of 64
      short8 bq[4][2];
#pragma unroll
      for (int ni = 0; ni < 4; ++ni)
#pragma unroll
        for (int k2 = 0; k2 < 2; ++k2)
          bq[ni][k2] = *(const short8*)(A.W2c +
              ((size_t)(org * 64 + c * 16 + s2 * 8 + k2 * 4 + lg) * D_DIM +
               wn * 64 + ni * 16 + lr) * 8);
      short8 af[2][2];
#pragma unroll
      for (int mi = 0; mi < 2; ++mi)
#pragma unroll
        for (int k2 = 0; k2 < 2; ++k2)
          af[mi][k2] = Hp[(s2 * 8 + k2 * 4 + lg) * 32 + mi * 16 + lr];
#pragma unroll
      for (int mi = 0; mi < 2; ++mi)
#pragma unroll
        for (int ni = 0; ni < 4; ++ni)
#pragma unroll
          for (int k2 = 0; k2 < 2; ++k2)
            sp[mi][ni] = __builtin_amdgcn_mfma_f32_16x16x32_bf16(
                af[mi][k2], bq[ni][k2], sp[mi][ni], 0, 0, 0);
    }
  }
#pragma unroll
  for (int mi = 0; mi < 2; ++mi)
#pragma unroll
    for (int r = 0; r < 4; ++r) {
      const int row = m0 + mi * 16 + lg * 4 + r;
      const bool has = A.stats[row].x > 0;
#pragma unroll
      for (int ni = 0; ni < 4; ++ni) {
        const int col = wn * 64 + ni * 16 + lr;
        const float sv = A.S[(size_t)row * D_DIM + col];
        A.out[(size_t)row * 261 + col] =
            has ? sv + 0.1f * (sp[mi][ni][r] + A.b2[org * D_DIM + col]) : sv;
      }
    }
}

// ---------------------------------------------------------------------------
// per-agent finish (wave/agent, 4 agents per block)
// ---------------------------------------------------------------------------
__device__ __forceinline__ void finish4(const Args& A, int ftask) {
  const int t = threadIdx.x;
  const int w = t >> 6, l = t & 63;
  const int i = ftask * 4 + w;
  const int4 stv = A.stats[i];
  const int cnt = stv.x, mass = stv.y, fi = stv.z, enemy = stv.w;
  float po = 0.f, pin = 0.f;
  if (cnt > 0) {
    short8 av = *(const short8*)(A.Abf + (size_t)i * H_DIM + l * 8);
    short8 bv = *(const short8*)(A.Bbf + (size_t)i * H_DIM + l * 8);
    const int nn = cnt < NB_CAP ? cnt : NB_CAP;
    for (int s = 0; s < nn; ++s) {
      const int j = A.nbl[i * NB_CAP + s];
      short8 bj = *(const short8*)(A.Bbf + (size_t)j * H_DIM + l * 8);
      short8 aj = *(const short8*)(A.Abf + (size_t)j * H_DIM + l * 8);
#pragma unroll
      for (int k2 = 0; k2 < 8; ++k2) {
        po  += bf2f((ushort_t)av[k2]) * bf2f((ushort_t)bj[k2]);
        pin += bf2f((ushort_t)bv[k2]) * bf2f((ushort_t)aj[k2]);
      }
    }
#pragma unroll
    for (int m2 = 1; m2 < 64; m2 <<= 1) {
      po  += __shfl_xor(po,  m2, 64);
      pin += __shfl_xor(pin, m2, 64);
    }
  }
  if (l == 0) {
    const float denom = fmaxf((float)cnt, 1.0f);
    const float invs = 0.044194173824159216f;   // 1/sqrt(512)
    const float ni_v = (cnt > 0) ? (po - pin) * invs / denom : 0.f;
    const int2 p2 = ((const int2*)A.positions)[i];
    const float res = A.resource_grid[p2.y * GRID_SZ + p2.x];
    const float e = A.energies[i];
    const int r = A.roles[i];
    float e_fi   = e + 0.03f * (float)mass + 0.02f * res - 0.04f * (float)enemy - 0.01f;
    float e_mass = e * 0.98f + 0.02f * ((fi > 0) ? 1.f : 0.f) + 0.01f * res - 0.02f * (float)enemy;
    float ne = (r == 1) ? e_fi : e_mass;
    ne = fminf(fmaxf(ne, 0.f), 1.f);
    const bool can_fi = (ne > 0.5f) && (mass >= 2) && (fi == 0) && (enemy == 0);
    const bool loses = (mass < 1) || (ne < 0.15f) || (enemy > fi + 1);
    const int nr = (r == 0) ? (can_fi ? 1 : 0) : ((r == 1) ? (loses ? 0 : 1) : r);
    float* orow = A.out + (size_t)i * 261;
    orow[256] = ni_v;
    orow[257] = ne;
    orow[258] = (nr == 0) ? 1.f : 0.f;
    orow[259] = (nr == 1) ? 1.f : 0.f;
    orow[260] = (nr == 2) ? 1.f : 0.f;
  }
}

// ---------------------------------------------------------------------------
// d1: packs (0..1343) + scan (1344..1919)
// d2: row_mlp (0..143, launched first) + A/B tiles (144..1295)
// d3: finish (1152)
// ---------------------------------------------------------------------------
__global__ __launch_bounds__(256) void k_prep(Args A) {
  __shared__ __align__(16) char smem[19584];
  if (blockIdx.x < 1344) pack_task(A, blockIdx.x);
  else                   scan_task(A, blockIdx.x - 1344, smem);
}
__global__ __launch_bounds__(256) void k_main(Args A) {
  __shared__ __align__(16) char smem[32768];
  if (blockIdx.x < 144) row_mlp(A, blockIdx.x, smem);
  else                  gemm_tile(A, blockIdx.x - 144, smem);
}
__global__ __launch_bounds__(256) void k_fin(Args A) {
  finish4(A, blockIdx.x);
}

extern "C" void kernel_launch(void* const* d_in, const int* in_sizes, int n_in,
                              void* d_out, int out_size, void* d_ws, size_t ws_size,
                              hipStream_t stream) {
  char* ws = (char*)d_ws;
  Args a;
  a.S             = (const float*)d_in[0];
  a.energies      = (const float*)d_in[1];
  a.resource_grid = (const float*)d_in[2];
  a.W_out         = (const float*)d_in[3];
  a.b_out         = (const float*)d_in[4];
  a.W_in          = (const float*)d_in[5];
  a.b_in          = (const float*)d_in[6];
  a.W1            = (const float*)d_in[7];
  a.b1            = (const float*)d_in[8];
  a.W2            = (const float*)d_in[9];
  a.b2            = (const float*)d_in[10];
  a.roles         = (const int*)d_in[11];
  a.positions     = (const int*)d_in[13];
  a.Sc    = (ushort_t*)(ws);              //  2,359,296 B
  a.Wc    = (ushort_t*)(ws +  2359296);   //  2,359,296 B
  a.W2c   = (ushort_t*)(ws +  4718592);   //    786,432 B
  a.Abf   = (ushort_t*)(ws +  5505024);   //  4,718,592 B
  a.Bbf   = (ushort_t*)(ws + 10223616);   //  4,718,592 B
  a.stats = (int4*)    (ws + 14942208);   //     73,728 B
  a.nbl   = (int*)     (ws + 15015936);   //    884,736 B  -> 15.9 MB total
  a.out   = (float*)d_out;

  k_prep<<<1920, 256, 0, stream>>>(a);
  k_main<<<1296, 256, 0, stream>>>(a);
  k_fin <<<1152, 256, 0, stream>>>(a);
}

// Round 9
// 44.671 us; speedup vs baseline: 1.3415x; 1.3415x over previous
//
#include <hip/hip_runtime.h>

#define M_AG   4608
#define NPO    1536
#define D_DIM  256
#define H_DIM  512
#define NBIG   1536
#define GRID_SZ 256
#define NB_CAP 48

typedef __attribute__((ext_vector_type(8))) short short8;
typedef __attribute__((ext_vector_type(4))) float f32x4;
typedef unsigned short ushort_t;
typedef unsigned long long u64;

struct Args {
  const float *S, *W_out, *W_in, *W1, *W2, *b_out, *b_in, *b1, *b2;
  const float *energies, *resource_grid;
  const int *roles, *positions;
  ushort_t *Sc, *Wc, *W2c, *Hc, *Abf, *Bbf;
  int4 *stats;
  int *nbl;
  float *out;
};

__device__ __forceinline__ ushort_t f2bf(float f) {
  unsigned int u = __builtin_bit_cast(unsigned int, f);
  unsigned int r = (u + 0x7FFFu + ((u >> 16) & 1u)) >> 16;   // RNE, finite inputs
  return (ushort_t)r;
}
__device__ __forceinline__ float bf2f(ushort_t u) {
  return __builtin_bit_cast(float, (unsigned int)u << 16);
}
__device__ __forceinline__ float tanh_fast(float x) {
  float e = __builtin_amdgcn_exp2f(x * 2.8853900817779268f);  // exp(2x)
  return 1.f - 2.f * __builtin_amdgcn_rcpf(e + 1.f);
}
__device__ __forceinline__ void gl_lds16(const ushort_t* g, ushort_t* l) {
  __builtin_amdgcn_global_load_lds(
      (const __attribute__((address_space(1))) unsigned int*)g,
      (__attribute__((address_space(3))) unsigned int*)l, 16, 0, 0);
}
#define VM0_BAR() do { asm volatile("s_waitcnt vmcnt(0)" ::: "memory"); \
                       __builtin_amdgcn_s_barrier(); } while (0)

// ---------------------------------------------------------------------------
// pack tasks (0..1343): Sc [32][4608][8], Wc [3][32][1536][8], W2c [3][64][256][8]
// ---------------------------------------------------------------------------
__device__ __forceinline__ void pack_task(const Args& A, int task) {
  const int t = threadIdx.x;
  if (task < 576) {
    int idx = task * 256 + t;
    int kc = idx / M_AG, m = idx - kc * M_AG;
    const float* p = A.S + (size_t)m * D_DIM + kc * 8;
    ushort_t* d = A.Sc + (size_t)idx * 8;
#pragma unroll
    for (int j = 0; j < 8; ++j) d[j] = f2bf(p[j]);
  } else if (task < 1152) {
    int idx = (task - 576) * 256 + t;
    int org = idx / (32 * NBIG);
    int rem = idx - org * (32 * NBIG);
    int kc = rem / NBIG, n = rem - kc * NBIG;
    int which = n >> 9, nl = n & 511;
    const float* Wsel = (which == 0 ? A.W_out : which == 1 ? A.W_in : A.W1);
    const float* p = Wsel + (size_t)org * (D_DIM * H_DIM) + (size_t)kc * 8 * H_DIM + nl;
    ushort_t* d = A.Wc + (size_t)idx * 8;
#pragma unroll
    for (int j = 0; j < 8; ++j) d[j] = f2bf(p[(size_t)j * H_DIM]);
  } else {
    int idx = (task - 1152) * 256 + t;
    int org = idx / (64 * D_DIM);
    int rem = idx - org * (64 * D_DIM);
    int kc = rem >> 8, n = rem & 255;
    const float* p = A.W2 + (size_t)org * (H_DIM * D_DIM) + (size_t)kc * 8 * D_DIM + n;
    ushort_t* d = A.W2c + (size_t)idx * 8;
#pragma unroll
    for (int j = 0; j < 8; ++j) d[j] = f2bf(p[(size_t)j * D_DIM]);
  }
}

// ---------------------------------------------------------------------------
// neighbor scan: 8 agents/task (wave/agent x2), ballot-ordered ascending list
// ---------------------------------------------------------------------------
__device__ __forceinline__ void scan_task(const Args& A, int stask, char* smem) {
  const int t = threadIdx.x;
  int* pk = (int*)smem;                 // x | y<<8 | role<<16
  u64* r0m = (u64*)(smem + 18432);
  u64* r1m = r0m + 72;
  for (int j = t; j < M_AG; j += 256) {
    int2 p2 = ((const int2*)A.positions)[j];
    pk[j] = p2.x | (p2.y << 8) | (A.roles[j] << 16);
  }
  __syncthreads();
  const int w = t >> 6, l = t & 63;
  for (int g = w; g < 72; g += 4) {
    int rj = pk[g * 64 + l] >> 16;
    u64 m0 = __ballot(rj == 0);
    u64 m1 = __ballot(rj == 1);
    if (l == 0) { r0m[g] = m0; r1m[g] = m1; }
  }
  __syncthreads();
  const int base_i = stask * 8;
#pragma unroll
  for (int rep = 0; rep < 2; ++rep) {
    const int i = base_i + rep * 4 + w;
    const int pi = pk[i];
    const int xi = pi & 255, yi = (pi >> 8) & 255;
    const int org = (i >= NPO) + (i >= 2 * NPO);   // org_ids = repeat(arange(3),1536)
    const int olo = org * NPO, ohi = olo + NPO;
    int nbn = 0, mass = 0, fi = 0, enemy = 0;
    for (int bs = olo; bs < ohi; bs += 64) {       // same-org groups (24)
      int j = bs + l;
      int pj = pk[j];
      int dx = (pj & 255) - xi, dy = ((pj >> 8) & 255) - yi;
      bool in_r = (dx * dx + dy * dy <= 25) && (j != i);
      u64 ms = __ballot(in_r);
      if (ms) {
        int g = bs >> 6;
        mass += __popcll(ms & r0m[g]);
        fi   += __popcll(ms & r1m[g]);
        if (in_r) {
          int slot = nbn + __popcll(ms & ((1ull << l) - 1ull));
          if (slot < NB_CAP) A.nbl[i * NB_CAP + slot] = j;   // ascending j
        }
        nbn += __popcll(ms);
      }
    }
#pragma unroll
    for (int half = 0; half < 2; ++half) {         // enemy groups (48)
      const int lo = half ? ohi : 0;
      const int hi = half ? M_AG : olo;
      for (int bs = lo; bs < hi; bs += 64) {
        int pj = pk[bs + l];
        int dx = (pj & 255) - xi, dy = ((pj >> 8) & 255) - yi;
        u64 ms = __ballot(dx * dx + dy * dy <= 25);
        enemy += __popcll(ms & r1m[bs >> 6]);
      }
    }
    if (l == 0) A.stats[i] = make_int4(nbn, mass, fi, enemy);
  }
}

// ---------------------------------------------------------------------------
// GEMM tile: [A|B|H1] = tanh(S*[W_out|W_in|W1]+bias); 64x64, BK=64, 4 steps,
// dbuf LDS, STAGE(next) in flight across VM0_BAR (r7-proven, unchanged).
// ---------------------------------------------------------------------------
__device__ __forceinline__ void gemm_tile(const Args& A, int tix, char* smem) {
  ushort_t* As = (ushort_t*)smem;
  ushort_t* Bs = (ushort_t*)(smem + 16384);
  const int t = threadIdx.x;
  const int w = t >> 6, l = t & 63;
  const int wm = w >> 1, wn = w & 1;
  const int lr = l & 15, lg = l >> 4;
  const int bx = tix % 24, by = tix / 24;
  const int n0 = bx * 64, m0 = by * 64;
  const int org = m0 / NPO;
  const int which = n0 >> 9, nlb = n0 & 511;
  const int g0 = t >> 6, r0 = t & 63, g1 = 4 + g0;
  const size_t wbase = (size_t)org * 32;

  f32x4 acc[2][2] = {};

  auto STAGE = [&](int s, int p) {
    const int kg = s * 8;
    ushort_t* Ad = As + p * 4096;
    ushort_t* Bd = Bs + p * 4096;
    gl_lds16(A.Sc + ((size_t)(kg + g0) * M_AG + m0 + r0) * 8, Ad + (size_t)t * 8);
    gl_lds16(A.Sc + ((size_t)(kg + g1) * M_AG + m0 + r0) * 8, Ad + (size_t)(t + 256) * 8);
    gl_lds16(A.Wc + ((wbase + kg + g0) * NBIG + n0 + r0) * 8, Bd + (size_t)t * 8);
    gl_lds16(A.Wc + ((wbase + kg + g1) * NBIG + n0 + r0) * 8, Bd + (size_t)(t + 256) * 8);
  };

  STAGE(0, 0);
  VM0_BAR();
  for (int s = 0; s < 4; ++s) {
    const int p = s & 1;
    if (s < 3) STAGE(s + 1, p ^ 1);      // in flight during compute
    const short8* Ap = (const short8*)(As + p * 4096);
    const short8* Bp = (const short8*)(Bs + p * 4096);
    short8 af[2][2], bf_[2][2];
#pragma unroll
    for (int k2 = 0; k2 < 2; ++k2) {
#pragma unroll
      for (int mi = 0; mi < 2; ++mi)
        af[mi][k2] = Ap[(k2 * 4 + lg) * 64 + wm * 32 + mi * 16 + lr];
#pragma unroll
      for (int ni = 0; ni < 2; ++ni)
        bf_[ni][k2] = Bp[(k2 * 4 + lg) * 64 + wn * 32 + ni * 16 + lr];
    }
#pragma unroll
    for (int mi = 0; mi < 2; ++mi)
#pragma unroll
      for (int ni = 0; ni < 2; ++ni)
#pragma unroll
        for (int k2 = 0; k2 < 2; ++k2)
          acc[mi][ni] = __builtin_amdgcn_mfma_f32_16x16x32_bf16(
              af[mi][k2], bf_[ni][k2], acc[mi][ni], 0, 0, 0);
    VM0_BAR();
  }

  const float* bias = (which == 0 ? A.b_out : which == 1 ? A.b_in : A.b1) + (size_t)org * H_DIM;
  ushort_t* dst = (which == 0) ? A.Abf : A.Bbf;
#pragma unroll
  for (int ni = 0; ni < 2; ++ni) {
    const int nl = nlb + wn * 32 + ni * 16 + lr;
    const float bb = bias[nl];
#pragma unroll
    for (int mi = 0; mi < 2; ++mi)
#pragma unroll
      for (int r = 0; r < 4; ++r) {
        const int row = m0 + wm * 32 + mi * 16 + lg * 4 + r;
        ushort_t hv = f2bf(tanh_fast(acc[mi][ni][r] + bb));
        if (which < 2) dst[(size_t)row * H_DIM + nl] = hv;
        else           A.Hc[((size_t)(nl >> 3) * M_AG + row) * 8 + (nl & 7)] = hv;
      }
  }
}

// ---------------------------------------------------------------------------
// SP tile 32x64 (576 blocks, 2.25/CU): SP = H1*W2 + b2, K=512 (8 steps, dbuf),
// fused epilogue: out[row][0:256] = has_nb ? states + 0.1*SP : states.
// Waves 2m x 2n; per wave 1 m-frag x 2 n-frags.
// ---------------------------------------------------------------------------
__device__ __forceinline__ void sp_tile(const Args& A, int s_ix, char* smem) {
  ushort_t* As = (ushort_t*)smem;              // [2][8 kg][32 row][8] = 2x4KB
  ushort_t* Bs = (ushort_t*)(smem + 8192);     // [2][8 kg][64 col][8] = 2x8KB
  const int t = threadIdx.x;
  const int w = t >> 6, l = t & 63;
  const int wm = w >> 1, wn = w & 1;
  const int lr = l & 15, lg = l >> 4;
  const int bx = s_ix & 3, by = s_ix >> 2;
  const int n0 = bx * 64, m0 = by * 32;
  const int org = m0 / NPO;
  const int akg = t >> 5, arow = t & 31;       // A: 1 chunk/thread
  const int bg0 = t >> 6, bc0 = t & 63, bg1 = 4 + bg0;   // B: 2 chunks/thread
  const size_t w2base = (size_t)org * 64;

  f32x4 acc[2] = {};

  auto STAGE = [&](int s, int p) {
    const int kg = s * 8;
    ushort_t* Ad = As + p * 2048;
    ushort_t* Bd = Bs + p * 4096;
    gl_lds16(A.Hc + ((size_t)(kg + akg) * M_AG + m0 + arow) * 8, Ad + (size_t)t * 8);
    gl_lds16(A.W2c + ((w2base + kg + bg0) * D_DIM + n0 + bc0) * 8, Bd + (size_t)t * 8);
    gl_lds16(A.W2c + ((w2base + kg + bg1) * D_DIM + n0 + bc0) * 8, Bd + (size_t)(t + 256) * 8);
  };

  STAGE(0, 0);
  VM0_BAR();
  for (int s = 0; s < 8; ++s) {
    const int p = s & 1;
    if (s < 7) STAGE(s + 1, p ^ 1);
    const short8* Ap = (const short8*)(As + p * 2048);
    const short8* Bp = (const short8*)(Bs + p * 4096);
    short8 af[2], bq[2][2];
#pragma unroll
    for (int k2 = 0; k2 < 2; ++k2) {
      af[k2] = Ap[(k2 * 4 + lg) * 32 + wm * 16 + lr];
#pragma unroll
      for (int ni = 0; ni < 2; ++ni)
        bq[ni][k2] = Bp[(k2 * 4 + lg) * 64 + wn * 32 + ni * 16 + lr];
    }
#pragma unroll
    for (int ni = 0; ni < 2; ++ni)
#pragma unroll
      for (int k2 = 0; k2 < 2; ++k2)
        acc[ni] = __builtin_amdgcn_mfma_f32_16x16x32_bf16(af[k2], bq[ni][k2], acc[ni], 0, 0, 0);
    VM0_BAR();
  }
#pragma unroll
  for (int r = 0; r < 4; ++r) {
    const int row = m0 + wm * 16 + lg * 4 + r;
    const bool has = A.stats[row].x > 0;
#pragma unroll
    for (int ni = 0; ni < 2; ++ni) {
      const int col = n0 + wn * 32 + ni * 16 + lr;
      const float sv = A.S[(size_t)row * D_DIM + col];
      A.out[(size_t)row * 261 + col] =
          has ? sv + 0.1f * (acc[ni][r] + A.b2[org * D_DIM + col]) : sv;
    }
  }
}

// ---------------------------------------------------------------------------
// per-agent finish (wave/agent, 4 agents per block)
// ---------------------------------------------------------------------------
__device__ __forceinline__ void finish4(const Args& A, int ftask) {
  const int t = threadIdx.x;
  const int w = t >> 6, l = t & 63;
  const int i = ftask * 4 + w;
  const int4 stv = A.stats[i];
  const int cnt = stv.x, mass = stv.y, fi = stv.z, enemy = stv.w;
  float po = 0.f, pin = 0.f;
  if (cnt > 0) {
    short8 av = *(const short8*)(A.Abf + (size_t)i * H_DIM + l * 8);
    short8 bv = *(const short8*)(A.Bbf + (size_t)i * H_DIM + l * 8);
    const int nn = cnt < NB_CAP ? cnt : NB_CAP;
    for (int s = 0; s < nn; ++s) {
      const int j = A.nbl[i * NB_CAP + s];
      short8 bj = *(const short8*)(A.Bbf + (size_t)j * H_DIM + l * 8);
      short8 aj = *(const short8*)(A.Abf + (size_t)j * H_DIM + l * 8);
#pragma unroll
      for (int k2 = 0; k2 < 8; ++k2) {
        po  += bf2f((ushort_t)av[k2]) * bf2f((ushort_t)bj[k2]);
        pin += bf2f((ushort_t)bv[k2]) * bf2f((ushort_t)aj[k2]);
      }
    }
#pragma unroll
    for (int m2 = 1; m2 < 64; m2 <<= 1) {
      po  += __shfl_xor(po,  m2, 64);
      pin += __shfl_xor(pin, m2, 64);
    }
  }
  if (l == 0) {
    const float denom = fmaxf((float)cnt, 1.0f);
    const float invs = 0.044194173824159216f;   // 1/sqrt(512)
    const float ni_v = (cnt > 0) ? (po - pin) * invs / denom : 0.f;
    const int2 p2 = ((const int2*)A.positions)[i];
    const float res = A.resource_grid[p2.y * GRID_SZ + p2.x];
    const float e = A.energies[i];
    const int r = A.roles[i];
    float e_fi   = e + 0.03f * (float)mass + 0.02f * res - 0.04f * (float)enemy - 0.01f;
    float e_mass = e * 0.98f + 0.02f * ((fi > 0) ? 1.f : 0.f) + 0.01f * res - 0.02f * (float)enemy;
    float ne = (r == 1) ? e_fi : e_mass;
    ne = fminf(fmaxf(ne, 0.f), 1.f);
    const bool can_fi = (ne > 0.5f) && (mass >= 2) && (fi == 0) && (enemy == 0);
    const bool loses = (mass < 1) || (ne < 0.15f) || (enemy > fi + 1);
    const int nr = (r == 0) ? (can_fi ? 1 : 0) : ((r == 1) ? (loses ? 0 : 1) : r);
    float* orow = A.out + (size_t)i * 261;
    orow[256] = ni_v;
    orow[257] = ne;
    orow[258] = (nr == 0) ? 1.f : 0.f;
    orow[259] = (nr == 1) ? 1.f : 0.f;
    orow[260] = (nr == 2) ? 1.f : 0.f;
  }
}

// ---------------------------------------------------------------------------
// d1: packs (1344)
// d2: scan FIRST (0..575, overlaps GEMM ramp), GEMM tiles (576..2303)
// d3: SP 32x64 tiles (0..575) + finish (576..1727)
// ---------------------------------------------------------------------------
__global__ __launch_bounds__(256) void k_prep(Args A) {
  pack_task(A, blockIdx.x);
}
__global__ __launch_bounds__(256) void k_main(Args A) {
  __shared__ __align__(16) char smem[32768];
  if (blockIdx.x < 576) scan_task(A, blockIdx.x, smem);
  else                  gemm_tile(A, blockIdx.x - 576, smem);
}
__global__ __launch_bounds__(256) void k_fin(Args A) {
  __shared__ __align__(16) char smem[24576];
  if (blockIdx.x < 576) sp_tile(A, blockIdx.x, smem);
  else                  finish4(A, blockIdx.x - 576);
}

extern "C" void kernel_launch(void* const* d_in, const int* in_sizes, int n_in,
                              void* d_out, int out_size, void* d_ws, size_t ws_size,
                              hipStream_t stream) {
  char* ws = (char*)d_ws;
  Args a;
  a.S             = (const float*)d_in[0];
  a.energies      = (const float*)d_in[1];
  a.resource_grid = (const float*)d_in[2];
  a.W_out         = (const float*)d_in[3];
  a.b_out         = (const float*)d_in[4];
  a.W_in          = (const float*)d_in[5];
  a.b_in          = (const float*)d_in[6];
  a.W1            = (const float*)d_in[7];
  a.b1            = (const float*)d_in[8];
  a.W2            = (const float*)d_in[9];
  a.b2            = (const float*)d_in[10];
  a.roles         = (const int*)d_in[11];
  a.positions     = (const int*)d_in[13];
  a.Sc    = (ushort_t*)(ws);              //  2,359,296 B
  a.Wc    = (ushort_t*)(ws +  2359296);   //  2,359,296 B
  a.W2c   = (ushort_t*)(ws +  4718592);   //    786,432 B
  a.Hc    = (ushort_t*)(ws +  5505024);   //  4,718,592 B
  a.Abf   = (ushort_t*)(ws + 10223616);   //  4,718,592 B
  a.Bbf   = (ushort_t*)(ws + 14942208);   //  4,718,592 B
  a.stats = (int4*)    (ws + 19660800);   //     73,728 B
  a.nbl   = (int*)     (ws + 19734528);   //    884,736 B  -> 20.6 MB total
  a.out   = (float*)d_out;

  k_prep<<<1344, 256, 0, stream>>>(a);
  k_main<<<2304, 256, 0, stream>>>(a);
  k_fin <<<1728, 256, 0, stream>>>(a);
}